// Round 1
// baseline (2284.795 us; speedup 1.0000x reference)
//
#include <hip/hip_runtime.h>
#include <math.h>

#define DEV __device__ __forceinline__

static constexpr int BB = 4, SS = 512, LL = 512, HH = 32;
static constexpr float MAXN  = 1.0f - 1e-5f;
static constexpr float MAXN2 = MAXN * MAXN;

DEV float dot8(const float* a, const float* b) {
  float s0 = a[0]*b[0], s1 = a[1]*b[1], s2 = a[2]*b[2], s3 = a[3]*b[3];
  float s4 = a[4]*b[4], s5 = a[5]*b[5], s6 = a[6]*b[6], s7 = a[7]*b[7];
  return ((s0+s1)+(s2+s3)) + ((s4+s5)+(s6+s7));
}

DEV void load8(float* d, const float* p) {
  float4 a = *(const float4*)p;
  float4 b = *(const float4*)(p + 4);
  d[0]=a.x; d[1]=a.y; d[2]=a.z; d[3]=a.w;
  d[4]=b.x; d[5]=b.y; d[6]=b.z; d[7]=b.w;
}

DEV void store8(float* p, const float* d) {
  *(float4*)p       = make_float4(d[0], d[1], d[2], d[3]);
  *(float4*)(p + 4) = make_float4(d[4], d[5], d[6], d[7]);
}

// project: rare path needs the rescale; common path is dot + compare only
DEV void project8(float* x) {
  float n2 = dot8(x, x) + 1e-15f;
  if (n2 > MAXN2) {
    float s = MAXN * rsqrtf(n2);
    #pragma unroll
    for (int i = 0; i < 8; ++i) x[i] *= s;
  }
}

DEV void logmap0_8(float* o, const float* x) {
  float t[8];
  #pragma unroll
  for (int i = 0; i < 8; ++i) t[i] = x[i];
  project8(t);
  float n2 = dot8(t, t) + 1e-15f;
  float n  = sqrtf(n2);
  float c  = fminf(n, 1.0f - 1e-7f);
  float at = 0.5f * __logf(__fdividef(1.0f + c, 1.0f - c));  // artanh
  float r  = at * rsqrtf(n2);
  #pragma unroll
  for (int i = 0; i < 8; ++i) o[i] = t[i] * r;
}

DEV void expmap0_8(float* o, const float* u) {
  float n2 = dot8(u, u) + 1e-15f;
  float n  = sqrtf(n2);
  float e  = __expf(2.0f * n);
  float th = 1.0f - __fdividef(2.0f, e + 1.0f);   // tanh(n), inf-safe
  float r  = th * rsqrtf(n2);
  #pragma unroll
  for (int i = 0; i < 8; ++i) o[i] = u[i] * r;
  project8(o);
}

DEV void madd8(float* o, const float* x, const float* y) {
  float x2 = dot8(x, x), y2 = dot8(y, y), xy = dot8(x, y);
  float cx  = 1.0f + 2.0f*xy + y2;
  float cy  = 1.0f - x2;
  float den = 1.0f + 2.0f*xy + x2*y2;
  float rd  = __fdividef(1.0f, den);
  #pragma unroll
  for (int i = 0; i < 8; ++i) o[i] = (cx*x[i] + cy*y[i]) * rd;
  project8(o);
}

DEV void matvec8(float* o, const float* M, const float* u) {
  #pragma unroll
  for (int e = 0; e < 8; ++e) o[e] = dot8(M + 8*e, u);
}

// ---------------- input pre-pass: ax_g = expmap0(U_g @ logmap0(project(we[x]))) ----------------
__global__ void prep_kernel(const int* __restrict__ x, const float* __restrict__ wemb,
                            const float* __restrict__ Uz, const float* __restrict__ Ur,
                            const float* __restrict__ Uh,
                            float* __restrict__ axz, float* __restrict__ axr, float* __restrict__ axh)
{
  int t = blockIdx.x * 256 + threadIdx.x;
  if (t >= BB * SS * HH) return;
  int hh = t & (HH - 1);
  int bs = t >> 5;
  int idx = x[bs];
  float we[8]; load8(we, wemb + ((size_t)idx * HH + hh) * 8);
  project8(we);
  float lx[8]; logmap0_8(lx, we);
  float v[8], a[8];
  matvec8(v, Uz, lx); expmap0_8(a, v); store8(axz + (size_t)t * 8, a);
  matvec8(v, Ur, lx); expmap0_8(a, v); store8(axr + (size_t)t * 8, a);
  matvec8(v, Uh, lx); expmap0_8(a, v); store8(axh + (size_t)t * 8, a);
}

// ---------------- label pre-pass ----------------
__global__ void label_kernel(const float* __restrict__ lemb,
                             float* __restrict__ labP, float* __restrict__ l2o)
{
  int t = blockIdx.x * 256 + threadIdx.x;
  if (t >= LL * HH) return;
  float lv[8]; load8(lv, lemb + (size_t)t * 8);
  project8(lv);
  store8(labP + (size_t)t * 8, lv);
  l2o[t] = dot8(lv, lv);
}

// ---------------- GRU scan: 128 independent chains, one thread each ----------------
__global__ __launch_bounds__(64, 1) void gru_kernel(
    const float* __restrict__ Wzp, const float* __restrict__ Wrp, const float* __restrict__ Whp,
    const float* __restrict__ bzp, const float* __restrict__ brp, const float* __restrict__ bhp,
    const float* __restrict__ axz, const float* __restrict__ axr, const float* __restrict__ axh,
    float* __restrict__ enc, float* __restrict__ e2out)
{
  int id = blockIdx.x * 64 + threadIdx.x;
  if (id >= BB * HH) return;

  float wz[64], wr[64], wh[64];
  #pragma unroll
  for (int i = 0; i < 16; ++i) {
    float4 a = ((const float4*)Wzp)[i];
    wz[4*i]=a.x; wz[4*i+1]=a.y; wz[4*i+2]=a.z; wz[4*i+3]=a.w;
    float4 b = ((const float4*)Wrp)[i];
    wr[4*i]=b.x; wr[4*i+1]=b.y; wr[4*i+2]=b.z; wr[4*i+3]=b.w;
    float4 c = ((const float4*)Whp)[i];
    wh[4*i]=c.x; wh[4*i+1]=c.y; wh[4*i+2]=c.z; wh[4*i+3]=c.w;
  }
  float bz[8], br[8], bh[8];
  load8(bz, bzp); load8(br, brp); load8(bh, bhp);

  float st[8];
  #pragma unroll
  for (int i = 0; i < 8; ++i) st[i] = 0.0f;

  size_t off = ((size_t)(id >> 5) * SS * HH + (size_t)(id & 31)) * 8;
  const size_t stride = (size_t)HH * 8;

  float cz[8], cr[8], ch[8];
  load8(cz, axz + off); load8(cr, axr + off); load8(ch, axh + off);

  for (int s = 0; s < SS; ++s) {
    size_t noff = off + stride;
    size_t poff = (s + 1 < SS) ? noff : off;
    float nz[8], nr[8], nh[8];
    load8(nz, axz + poff); load8(nr, axr + poff); load8(nh, axh + poff);

    float lh[8]; logmap0_8(lh, st);

    float tmp[8], g1[8], g2[8], lg[8], zv[8], rv[8];
    // z gate
    matvec8(tmp, wz, lh);
    float az[8]; expmap0_8(az, tmp);
    madd8(g1, az, cz);
    madd8(g2, g1, bz);
    logmap0_8(lg, g2);
    #pragma unroll
    for (int i = 0; i < 8; ++i) zv[i] = __fdividef(1.0f, 1.0f + __expf(-lg[i]));
    // r gate
    matvec8(tmp, wr, lh);
    float ar[8]; expmap0_8(ar, tmp);
    madd8(g1, ar, cr);
    madd8(g2, g1, br);
    logmap0_8(lg, g2);
    #pragma unroll
    for (int i = 0; i < 8; ++i) rv[i] = __fdividef(1.0f, 1.0f + __expf(-lg[i]));
    // h_tilde: logmap0(expmap0(r*lh)) == r*lh  (norm < artanh(MAX_NORM) strictly)
    float u[8];
    #pragma unroll
    for (int i = 0; i < 8; ++i) u[i] = rv[i] * lh[i];
    matvec8(tmp, wh, u);
    float ah[8]; expmap0_8(ah, tmp);
    float t3[8], t4[8];
    madd8(t3, ah, ch);
    madd8(t4, t3, bh);
    // h_new = h ⊕ expmap0(z * logmap0((-h) ⊕ h_tilde))
    float mh[8];
    #pragma unroll
    for (int i = 0; i < 8; ++i) mh[i] = -st[i];
    float m[8]; madd8(m, mh, t4);
    float lm[8]; logmap0_8(lm, m);
    float w8[8];
    #pragma unroll
    for (int i = 0; i < 8; ++i) w8[i] = zv[i] * lm[i];
    float ee[8]; expmap0_8(ee, w8);
    float hn[8]; madd8(hn, st, ee);

    store8(enc + off, hn);
    e2out[off >> 3] = dot8(hn, hn);
    #pragma unroll
    for (int i = 0; i < 8; ++i) {
      st[i] = hn[i]; cz[i] = nz[i]; cr[i] = nr[i]; ch[i] = nh[i];
    }
    off = noff;
  }
}

// ---------------- poincare distance sums -> inter [B,L,S] ----------------
__global__ __launch_bounds__(256) void dist_kernel(
    const float* __restrict__ enc, const float* __restrict__ e2,
    const float* __restrict__ labP, const float* __restrict__ l2,
    float* __restrict__ inter)
{
  int blk = blockIdx.x;
  int lt = blk & 31, stile = (blk >> 5) & 31, b = blk >> 10;
  int li = threadIdx.x & 15, si = threadIdx.x >> 4;
  int s = stile * 16 + si, l = lt * 16 + li;

  const float* erow  = enc  + ((size_t)b * SS + s) * HH * 8;
  const float* e2row = e2   + ((size_t)b * SS + s) * HH;
  const float* lrow  = labP + (size_t)l * HH * 8;
  const float* l2row = l2   + (size_t)l * HH;

  float acc = 0.0f;
  #pragma unroll 4
  for (int hh = 0; hh < HH; ++hh) {
    float ev[8], lv[8];
    load8(ev, erow + hh * 8);
    load8(lv, lrow + hh * 8);
    float ev2 = e2row[hh], lv2 = l2row[hh];
    float el = dot8(ev, lv);
    float d2 = ev2 + lv2 - 2.0f * el;
    float den = fmaxf((1.0f - ev2) * (1.0f - lv2), 1e-15f);
    float zz = 1.0f + __fdividef(2.0f * d2, den);
    zz = fmaxf(zz, 1.0f + 1e-7f);
    acc += __logf(zz + sqrtf(zz * zz - 1.0f));   // arccosh
  }
  inter[((size_t)b * LL + l) * SS + s] = acc;
}

// ---------------- MLP stage 1: h = relu(inter @ W1^T + b1) ----------------
__global__ __launch_bounds__(256) void mlp1_kernel(
    const float* __restrict__ inter, const float* __restrict__ W1,
    const float* __restrict__ b1, float* __restrict__ hbuf)
{
  __shared__ float As[32][33];
  __shared__ float Bs[32][33];
  int t = threadIdx.x;
  int nt = blockIdx.x & 7, mt = blockIdx.x >> 3;
  int row0 = mt * 32, j0 = nt * 32;
  int li = t >> 4, ji = t & 15;
  float acc00 = 0.f, acc01 = 0.f, acc10 = 0.f, acc11 = 0.f;

  for (int k0 = 0; k0 < 512; k0 += 32) {
    __syncthreads();
    {
      int l = t >> 3, kk = (t & 7) * 4;
      float4 v = *(const float4*)(inter + (size_t)(row0 + l) * 512 + k0 + kk);
      As[l][kk] = v.x; As[l][kk+1] = v.y; As[l][kk+2] = v.z; As[l][kk+3] = v.w;
      float4 w = *(const float4*)(W1 + (size_t)(j0 + l) * 512 + k0 + kk);
      Bs[kk][l] = w.x; Bs[kk+1][l] = w.y; Bs[kk+2][l] = w.z; Bs[kk+3][l] = w.w;
    }
    __syncthreads();
    #pragma unroll
    for (int kk = 0; kk < 32; ++kk) {
      float a0 = As[li][kk],  a1 = As[li + 16][kk];
      float b0 = Bs[kk][ji],  b1v = Bs[kk][ji + 16];
      acc00 = fmaf(a0, b0, acc00);
      acc01 = fmaf(a0, b1v, acc01);
      acc10 = fmaf(a1, b0, acc10);
      acc11 = fmaf(a1, b1v, acc11);
    }
  }
  float bj0 = b1[j0 + ji], bj1 = b1[j0 + ji + 16];
  hbuf[(size_t)(row0 + li)      * 256 + j0 + ji]      = fmaxf(acc00 + bj0, 0.f);
  hbuf[(size_t)(row0 + li)      * 256 + j0 + ji + 16] = fmaxf(acc01 + bj1, 0.f);
  hbuf[(size_t)(row0 + li + 16) * 256 + j0 + ji]      = fmaxf(acc10 + bj0, 0.f);
  hbuf[(size_t)(row0 + li + 16) * 256 + j0 + ji + 16] = fmaxf(acc11 + bj1, 0.f);
}

// ---------------- MLP stage 2: out = h @ W2^T + b2 ----------------
__global__ void mlp2_kernel(const float* __restrict__ hbuf, const float* __restrict__ W2,
                            const float* __restrict__ b2, float* __restrict__ out)
{
  int t = threadIdx.x;
  int row = blockIdx.x * 4 + (t >> 6);
  int lane = t & 63;
  float v = 0.f;
  #pragma unroll
  for (int p = 0; p < 4; ++p) {
    int j = lane + p * 64;
    v = fmaf(hbuf[(size_t)row * 256 + j], W2[j], v);
  }
  #pragma unroll
  for (int off = 32; off > 0; off >>= 1) v += __shfl_xor(v, off);
  if (lane == 0) out[row] = v + b2[0];
}

extern "C" void kernel_launch(void* const* d_in, const int* in_sizes, int n_in,
                              void* d_out, int out_size, void* d_ws, size_t ws_size,
                              hipStream_t stream) {
  (void)in_sizes; (void)n_in; (void)out_size; (void)ws_size;
  const int*   x    = (const int*)d_in[0];
  const float* wemb = (const float*)d_in[1];
  const float* lemb = (const float*)d_in[2];
  const float* Wz = (const float*)d_in[3];
  const float* Wr = (const float*)d_in[4];
  const float* Wh = (const float*)d_in[5];
  const float* Uz = (const float*)d_in[6];
  const float* Ur = (const float*)d_in[7];
  const float* Uh = (const float*)d_in[8];
  const float* bz = (const float*)d_in[9];
  const float* br = (const float*)d_in[10];
  const float* bh = (const float*)d_in[11];
  const float* W1 = (const float*)d_in[12];
  const float* b1 = (const float*)d_in[13];
  const float* W2 = (const float*)d_in[14];
  const float* b2 = (const float*)d_in[15];
  float* out = (float*)d_out;

  float* p = (float*)d_ws;
  const size_t NBSH8 = (size_t)BB * SS * HH * 8;   // 524288
  float* axz  = p; p += NBSH8;
  float* axr  = p; p += NBSH8;
  float* axh  = p; p += NBSH8;
  float* enc  = p; p += NBSH8;
  float* e2   = p; p += (size_t)BB * SS * HH;      // 65536
  float* labP = p; p += (size_t)LL * HH * 8;       // 131072
  float* l2   = p; p += (size_t)LL * HH;           // 16384
  float* inter= p; p += (size_t)BB * LL * SS;      // 1048576
  float* hbuf = p; p += (size_t)BB * LL * 256;     // 524288

  prep_kernel <<<(BB * SS * HH) / 256, 256, 0, stream>>>(x, wemb, Uz, Ur, Uh, axz, axr, axh);
  label_kernel<<<(LL * HH) / 256, 256, 0, stream>>>(lemb, labP, l2);
  gru_kernel  <<<2, 64, 0, stream>>>(Wz, Wr, Wh, bz, br, bh, axz, axr, axh, enc, e2);
  dist_kernel <<<BB * (SS / 16) * (LL / 16), 256, 0, stream>>>(enc, e2, labP, l2, inter);
  mlp1_kernel <<<512, 256, 0, stream>>>(inter, W1, b1, hbuf);
  mlp2_kernel <<<512, 256, 0, stream>>>(hbuf, W2, b2, out);
}

// Round 2
// 805.895 us; speedup vs baseline: 2.8351x; 2.8351x over previous
//
#include <hip/hip_runtime.h>
#include <math.h>

#define DEV __device__ __forceinline__

static constexpr int BB = 4, SS = 512, LL = 512, HH = 32;
static constexpr float MAXN  = 1.0f - 1e-5f;
static constexpr float MAXN2 = MAXN * MAXN;

DEV float rcpf(float x) { return __builtin_amdgcn_rcpf(x); }
DEV float rsqf(float x) { return __builtin_amdgcn_rsqf(x); }

// ---------------- scalar helpers (prep/label/dist kernels) ----------------
DEV float dot8(const float* a, const float* b) {
  float s0 = a[0]*b[0], s1 = a[1]*b[1], s2 = a[2]*b[2], s3 = a[3]*b[3];
  float s4 = a[4]*b[4], s5 = a[5]*b[5], s6 = a[6]*b[6], s7 = a[7]*b[7];
  return ((s0+s1)+(s2+s3)) + ((s4+s5)+(s6+s7));
}

DEV void load8(float* d, const float* p) {
  float4 a = *(const float4*)p;
  float4 b = *(const float4*)(p + 4);
  d[0]=a.x; d[1]=a.y; d[2]=a.z; d[3]=a.w;
  d[4]=b.x; d[5]=b.y; d[6]=b.z; d[7]=b.w;
}

DEV void store8(float* p, const float* d) {
  *(float4*)p       = make_float4(d[0], d[1], d[2], d[3]);
  *(float4*)(p + 4) = make_float4(d[4], d[5], d[6], d[7]);
}

DEV void project8(float* x) {
  float n2 = dot8(x, x) + 1e-15f;
  if (n2 > MAXN2) {
    float s = MAXN * rsqf(n2);
    #pragma unroll
    for (int i = 0; i < 8; ++i) x[i] *= s;
  }
}

DEV void logmap0_8(float* o, const float* x) {
  float t[8];
  #pragma unroll
  for (int i = 0; i < 8; ++i) t[i] = x[i];
  project8(t);
  float n2 = dot8(t, t) + 1e-15f;
  float rs = rsqf(n2);
  float n  = n2 * rs;
  float c  = fminf(n, 1.0f - 1e-7f);
  float at = 0.5f * __logf((1.0f + c) * rcpf(1.0f - c));
  float r  = at * rs;
  #pragma unroll
  for (int i = 0; i < 8; ++i) o[i] = t[i] * r;
}

DEV void expmap0_8(float* o, const float* u) {
  float n2 = dot8(u, u) + 1e-15f;
  float rs = rsqf(n2);
  float n  = n2 * rs;
  float e  = __expf(2.0f * n);
  float th = 1.0f - 2.0f * rcpf(e + 1.0f);
  float r  = th * rs;
  #pragma unroll
  for (int i = 0; i < 8; ++i) o[i] = u[i] * r;
  project8(o);
}

DEV void matvec8(float* o, const float* M, const float* u) {
  #pragma unroll
  for (int e = 0; e < 8; ++e) o[e] = dot8(M + 8*e, u);
}

// ---------------- DPP helpers (gru kernel) ----------------
template<int CTRL>
DEV float dppf(float x) {
  int xi = __float_as_int(x);
  return __int_as_float(__builtin_amdgcn_update_dpp(xi, xi, CTRL, 0xF, 0xF, true));
}
// xor1 = quad_perm(1,0,3,2)=0xB1; xor2 = quad_perm(2,3,0,1)=0x4E;
// xor3 = quad_perm(3,2,1,0)=0x1B; xor7 = row_half_mirror=0x141.

DEV float grp8sum(float x) {
  x += dppf<0xB1>(x);
  x += dppf<0x4E>(x);
  x += dppf<0x141>(x);
  return x;
}

#define MV8(w, u0,u1,u2,u3,u4,u5,u6,u7) \
  ((((w[0]*(u0)) + (w[1]*(u1))) + ((w[2]*(u2)) + (w[3]*(u3)))) + \
   (((w[4]*(u4)) + (w[5]*(u5))) + ((w[6]*(u6)) + (w[7]*(u7)))))

// logmap0 of an already-in-ball point: lane component v, cached squared norm n2.
DEV float logmap_lane(float v, float n2) {
  float n2p = n2 + 1e-15f;
  float rs  = rsqf(n2p);
  float n   = n2p * rs;
  float c   = fminf(n, 1.0f - 1e-7f);
  float at  = 0.5f * __logf((1.0f + c) * rcpf(1.0f - c));
  return v * (at * rs);
}

DEV void expmap_lane(float v, float n2, float& o, float& o2) {
  float n2p = n2 + 1e-15f;
  float rs  = rsqf(n2p);
  float n   = n2p * rs;
  float e   = __expf(2.0f * n);
  float th  = 1.0f - 2.0f * rcpf(e + 1.0f);
  o  = v * (th * rs);
  o2 = th * th;
  if (o2 > MAXN2) { float sc = MAXN * rsqf(o2); o *= sc; o2 = MAXN2; }
}

// mobius add with cached squared norms; xy = <x,y> precomputed (group-uniform).
DEV void madd_lane(float x, float x2, float y, float y2, float xy,
                   float& o, float& o2) {
  float cx  = 1.0f + 2.0f*xy + y2;
  float cy  = 1.0f - x2;
  float den = 1.0f + 2.0f*xy + x2*y2;
  float rd  = rcpf(den);
  o = (cx*x + cy*y) * rd;
  float num2 = (cx*cx)*x2 + 2.0f*(cx*cy)*xy + (cy*cy)*y2;
  o2 = num2 * (rd * rd);
  if (o2 > MAXN2) { float sc = MAXN * rsqf(o2); o *= sc; o2 = MAXN2; }
}

DEV float sigm(float x) { return rcpf(1.0f + __expf(-x)); }

// ---------------- input pre-pass ----------------
__global__ void prep_kernel(const int* __restrict__ x, const float* __restrict__ wemb,
                            const float* __restrict__ Uz, const float* __restrict__ Ur,
                            const float* __restrict__ Uh,
                            float* __restrict__ axz, float* __restrict__ axr, float* __restrict__ axh,
                            float* __restrict__ axz2, float* __restrict__ axr2, float* __restrict__ axh2)
{
  int t = blockIdx.x * 256 + threadIdx.x;
  if (t >= BB * SS * HH) return;
  int hh = t & (HH - 1);
  int bs = t >> 5;
  int idx = x[bs];
  float we[8]; load8(we, wemb + ((size_t)idx * HH + hh) * 8);
  project8(we);
  float lx[8]; logmap0_8(lx, we);
  float v[8], a[8];
  matvec8(v, Uz, lx); expmap0_8(a, v); store8(axz + (size_t)t * 8, a); axz2[t] = dot8(a, a);
  matvec8(v, Ur, lx); expmap0_8(a, v); store8(axr + (size_t)t * 8, a); axr2[t] = dot8(a, a);
  matvec8(v, Uh, lx); expmap0_8(a, v); store8(axh + (size_t)t * 8, a); axh2[t] = dot8(a, a);
}

// ---------------- label pre-pass ----------------
__global__ void label_kernel(const float* __restrict__ lemb,
                             float* __restrict__ labP, float* __restrict__ l2o)
{
  int t = blockIdx.x * 256 + threadIdx.x;
  if (t >= LL * HH) return;
  float lv[8]; load8(lv, lemb + (size_t)t * 8);
  project8(lv);
  store8(labP + (size_t)t * 8, lv);
  l2o[t] = dot8(lv, lv);
}

// ---------------- GRU scan: 8 lanes per chain, DPP cross-lane ----------------
__global__ __launch_bounds__(64, 1) void gru_kernel(
    const float* __restrict__ Wzp, const float* __restrict__ Wrp, const float* __restrict__ Whp,
    const float* __restrict__ bzp, const float* __restrict__ brp, const float* __restrict__ bhp,
    const float* __restrict__ axz, const float* __restrict__ axr, const float* __restrict__ axh,
    const float* __restrict__ axz2, const float* __restrict__ axr2, const float* __restrict__ axh2,
    float* __restrict__ enc, float* __restrict__ e2out)
{
  const int lane = threadIdx.x;        // 0..63
  const int d    = lane & 7;           // dim within chain
  const int cg   = lane >> 3;          // chain within block (0..7)
  const int b    = blockIdx.x >> 2;
  const int h    = (blockIdx.x & 3) * 8 + cg;

  // per-lane weight rows, xor-permuted: w[k] = M[d][d^k]
  float wz[8], wr[8], wh[8];
  #pragma unroll
  for (int k = 0; k < 8; ++k) {
    wz[k] = Wzp[d*8 + (d^k)];
    wr[k] = Wrp[d*8 + (d^k)];
    wh[k] = Whp[d*8 + (d^k)];
  }
  float bzv = bzp[d], brv = brp[d], bhv = bhp[d];
  float bz2 = grp8sum(bzv*bzv);
  float br2 = grp8sum(brv*brv);
  float bh2 = grp8sum(bhv*bhv);

  float hv = 0.0f, h2 = 0.0f;

  size_t voff = ((size_t)b * SS * HH + h) * 8 + d;   // element offset, +HH*8 per step
  size_t soff = (size_t)b * SS * HH + h;             // scalar offset, +HH per step

  float cz = axz[voff], cr = axr[voff], ch = axh[voff];
  float cz2 = axz2[soff], cr2 = axr2[soff], ch2 = axh2[soff];

  #pragma unroll 1
  for (int s = 0; s < SS; ++s) {
    size_t nvoff = voff + HH*8, nsoff = soff + HH;
    size_t pv = (s + 1 < SS) ? nvoff : voff;
    size_t ps = (s + 1 < SS) ? nsoff : soff;
    float nz = axz[pv], nr = axr[pv], nh = axh[pv];
    float nz2 = axz2[ps], nr2 = axr2[ps], nh2 = axh2[ps];

    // lh = logmap0(h)
    float lh = logmap_lane(hv, h2);

    // shared permutes of lh
    float l1 = dppf<0xB1>(lh), l2 = dppf<0x4E>(lh), l3 = dppf<0x1B>(lh), l7 = dppf<0x141>(lh);
    float l4 = dppf<0x1B>(l7), l5 = dppf<0x4E>(l7), l6 = dppf<0xB1>(l7);

    float vz = MV8(wz, lh, l1, l2, l3, l4, l5, l6, l7);
    float vr = MV8(wr, lh, l1, l2, l3, l4, l5, l6, l7);

    float az, az2; expmap_lane(vz, grp8sum(vz*vz), az, az2);
    float ar, ar2; expmap_lane(vr, grp8sum(vr*vr), ar, ar2);

    // z gate
    float g1, g12; madd_lane(az, az2, cz, cz2, grp8sum(az*cz), g1, g12);
    float g2, g22; madd_lane(g1, g12, bzv, bz2, grp8sum(g1*bzv), g2, g22);
    float zv = sigm(logmap_lane(g2, g22));
    // r gate
    float q1, q12; madd_lane(ar, ar2, cr, cr2, grp8sum(ar*cr), q1, q12);
    float q2, q22; madd_lane(q1, q12, brv, br2, grp8sum(q1*brv), q2, q22);
    float rv = sigm(logmap_lane(q2, q22));

    // h_tilde: logmap0(expmap0(r*lh)) == r*lh (norm < artanh(MAX_NORM))
    float u = rv * lh;
    float u1 = dppf<0xB1>(u), u2p = dppf<0x4E>(u), u3 = dppf<0x1B>(u), u7 = dppf<0x141>(u);
    float u4 = dppf<0x1B>(u7), u5 = dppf<0x4E>(u7), u6 = dppf<0xB1>(u7);
    float vh = MV8(wh, u, u1, u2p, u3, u4, u5, u6, u7);
    float ah, ah2; expmap_lane(vh, grp8sum(vh*vh), ah, ah2);
    float t3, t32; madd_lane(ah, ah2, ch, ch2, grp8sum(ah*ch), t3, t32);
    float t4, t42; madd_lane(t3, t32, bhv, bh2, grp8sum(t3*bhv), t4, t42);

    // h_new = h ⊕ expmap0(z * logmap0((-h) ⊕ h_tilde))
    float mh = -hv;
    float m, m2; madd_lane(mh, h2, t4, t42, grp8sum(mh*t4), m, m2);
    float lm = logmap_lane(m, m2);
    float w  = zv * lm;
    float ee, ee2; expmap_lane(w, grp8sum(w*w), ee, ee2);
    float hn, hn2; madd_lane(hv, h2, ee, ee2, grp8sum(hv*ee), hn, hn2);

    enc[voff] = hn;
    if (d == 0) e2out[soff] = hn2;

    hv = hn; h2 = hn2;
    cz = nz; cr = nr; ch = nh;
    cz2 = nz2; cr2 = nr2; ch2 = nh2;
    voff = nvoff; soff = nsoff;
  }
}

// ---------------- poincare distance sums -> inter [B,L,S] ----------------
__global__ __launch_bounds__(256) void dist_kernel(
    const float* __restrict__ enc, const float* __restrict__ e2,
    const float* __restrict__ labP, const float* __restrict__ l2,
    float* __restrict__ inter)
{
  int blk = blockIdx.x;
  int lt = blk & 31, stile = (blk >> 5) & 31, b = blk >> 10;
  int li = threadIdx.x & 15, si = threadIdx.x >> 4;
  int s = stile * 16 + si, l = lt * 16 + li;

  const float* erow  = enc  + ((size_t)b * SS + s) * HH * 8;
  const float* e2row = e2   + ((size_t)b * SS + s) * HH;
  const float* lrow  = labP + (size_t)l * HH * 8;
  const float* l2row = l2   + (size_t)l * HH;

  float acc = 0.0f;
  #pragma unroll 4
  for (int hh = 0; hh < HH; ++hh) {
    float ev[8], lv[8];
    load8(ev, erow + hh * 8);
    load8(lv, lrow + hh * 8);
    float ev2 = e2row[hh], lv2 = l2row[hh];
    float el = dot8(ev, lv);
    float d2 = ev2 + lv2 - 2.0f * el;
    float den = fmaxf((1.0f - ev2) * (1.0f - lv2), 1e-15f);
    float zz = 1.0f + __fdividef(2.0f * d2, den);
    zz = fmaxf(zz, 1.0f + 1e-7f);
    acc += __logf(zz + sqrtf(zz * zz - 1.0f));   // arccosh
  }
  inter[((size_t)b * LL + l) * SS + s] = acc;
}

// ---------------- MLP stage 1: h = relu(inter @ W1^T + b1) ----------------
__global__ __launch_bounds__(256) void mlp1_kernel(
    const float* __restrict__ inter, const float* __restrict__ W1,
    const float* __restrict__ b1, float* __restrict__ hbuf)
{
  __shared__ float As[32][33];
  __shared__ float Bs[32][33];
  int t = threadIdx.x;
  int nt = blockIdx.x & 7, mt = blockIdx.x >> 3;
  int row0 = mt * 32, j0 = nt * 32;
  int li = t >> 4, ji = t & 15;
  float acc00 = 0.f, acc01 = 0.f, acc10 = 0.f, acc11 = 0.f;

  for (int k0 = 0; k0 < 512; k0 += 32) {
    __syncthreads();
    {
      int l = t >> 3, kk = (t & 7) * 4;
      float4 v = *(const float4*)(inter + (size_t)(row0 + l) * 512 + k0 + kk);
      As[l][kk] = v.x; As[l][kk+1] = v.y; As[l][kk+2] = v.z; As[l][kk+3] = v.w;
      float4 w = *(const float4*)(W1 + (size_t)(j0 + l) * 512 + k0 + kk);
      Bs[kk][l] = w.x; Bs[kk+1][l] = w.y; Bs[kk+2][l] = w.z; Bs[kk+3][l] = w.w;
    }
    __syncthreads();
    #pragma unroll
    for (int kk = 0; kk < 32; ++kk) {
      float a0 = As[li][kk],  a1 = As[li + 16][kk];
      float b0 = Bs[kk][ji],  b1v = Bs[kk][ji + 16];
      acc00 = fmaf(a0, b0, acc00);
      acc01 = fmaf(a0, b1v, acc01);
      acc10 = fmaf(a1, b0, acc10);
      acc11 = fmaf(a1, b1v, acc11);
    }
  }
  float bj0 = b1[j0 + ji], bj1 = b1[j0 + ji + 16];
  hbuf[(size_t)(row0 + li)      * 256 + j0 + ji]      = fmaxf(acc00 + bj0, 0.f);
  hbuf[(size_t)(row0 + li)      * 256 + j0 + ji + 16] = fmaxf(acc01 + bj1, 0.f);
  hbuf[(size_t)(row0 + li + 16) * 256 + j0 + ji]      = fmaxf(acc10 + bj0, 0.f);
  hbuf[(size_t)(row0 + li + 16) * 256 + j0 + ji + 16] = fmaxf(acc11 + bj1, 0.f);
}

// ---------------- MLP stage 2: out = h @ W2^T + b2 ----------------
__global__ void mlp2_kernel(const float* __restrict__ hbuf, const float* __restrict__ W2,
                            const float* __restrict__ b2, float* __restrict__ out)
{
  int t = threadIdx.x;
  int row = blockIdx.x * 4 + (t >> 6);
  int lane = t & 63;
  float v = 0.f;
  #pragma unroll
  for (int p = 0; p < 4; ++p) {
    int j = lane + p * 64;
    v = fmaf(hbuf[(size_t)row * 256 + j], W2[j], v);
  }
  #pragma unroll
  for (int off = 32; off > 0; off >>= 1) v += __shfl_xor(v, off);
  if (lane == 0) out[row] = v + b2[0];
}

extern "C" void kernel_launch(void* const* d_in, const int* in_sizes, int n_in,
                              void* d_out, int out_size, void* d_ws, size_t ws_size,
                              hipStream_t stream) {
  (void)in_sizes; (void)n_in; (void)out_size; (void)ws_size;
  const int*   x    = (const int*)d_in[0];
  const float* wemb = (const float*)d_in[1];
  const float* lemb = (const float*)d_in[2];
  const float* Wz = (const float*)d_in[3];
  const float* Wr = (const float*)d_in[4];
  const float* Wh = (const float*)d_in[5];
  const float* Uz = (const float*)d_in[6];
  const float* Ur = (const float*)d_in[7];
  const float* Uh = (const float*)d_in[8];
  const float* bz = (const float*)d_in[9];
  const float* br = (const float*)d_in[10];
  const float* bh = (const float*)d_in[11];
  const float* W1 = (const float*)d_in[12];
  const float* b1 = (const float*)d_in[13];
  const float* W2 = (const float*)d_in[14];
  const float* b2 = (const float*)d_in[15];
  float* out = (float*)d_out;

  float* p = (float*)d_ws;
  const size_t NBSH  = (size_t)BB * SS * HH;       // 65536
  const size_t NBSH8 = NBSH * 8;                   // 524288
  float* axz  = p; p += NBSH8;
  float* axr  = p; p += NBSH8;
  float* axh  = p; p += NBSH8;
  float* axz2 = p; p += NBSH;
  float* axr2 = p; p += NBSH;
  float* axh2 = p; p += NBSH;
  float* enc  = p; p += NBSH8;
  float* e2   = p; p += NBSH;
  float* labP = p; p += (size_t)LL * HH * 8;       // 131072
  float* l2   = p; p += (size_t)LL * HH;           // 16384
  float* inter= p; p += (size_t)BB * LL * SS;      // 1048576
  float* hbuf = p; p += (size_t)BB * LL * 256;     // 524288

  prep_kernel <<<(BB * SS * HH) / 256, 256, 0, stream>>>(x, wemb, Uz, Ur, Uh,
                                                         axz, axr, axh, axz2, axr2, axh2);
  label_kernel<<<(LL * HH) / 256, 256, 0, stream>>>(lemb, labP, l2);
  gru_kernel  <<<16, 64, 0, stream>>>(Wz, Wr, Wh, bz, br, bh,
                                      axz, axr, axh, axz2, axr2, axh2, enc, e2);
  dist_kernel <<<BB * (SS / 16) * (LL / 16), 256, 0, stream>>>(enc, e2, labP, l2, inter);
  mlp1_kernel <<<512, 256, 0, stream>>>(inter, W1, b1, hbuf);
  mlp2_kernel <<<512, 256, 0, stream>>>(hbuf, W2, b2, out);
}

// Round 3
// 583.198 us; speedup vs baseline: 3.9177x; 1.3819x over previous
//
#include <hip/hip_runtime.h>
#include <math.h>

#define DEV __device__ __forceinline__

static constexpr int BB = 4, SS = 512, LL = 512, HH = 32;
static constexpr float MAXN  = 1.0f - 1e-5f;
static constexpr float MAXN2 = MAXN * MAXN;

DEV float rcpf(float x) { return __builtin_amdgcn_rcpf(x); }
DEV float rsqf(float x) { return __builtin_amdgcn_rsqf(x); }

// ---------------- scalar helpers (prep/label/dist kernels) ----------------
DEV float dot8(const float* a, const float* b) {
  float s0 = a[0]*b[0], s1 = a[1]*b[1], s2 = a[2]*b[2], s3 = a[3]*b[3];
  float s4 = a[4]*b[4], s5 = a[5]*b[5], s6 = a[6]*b[6], s7 = a[7]*b[7];
  return ((s0+s1)+(s2+s3)) + ((s4+s5)+(s6+s7));
}

DEV void load8(float* d, const float* p) {
  float4 a = *(const float4*)p;
  float4 b = *(const float4*)(p + 4);
  d[0]=a.x; d[1]=a.y; d[2]=a.z; d[3]=a.w;
  d[4]=b.x; d[5]=b.y; d[6]=b.z; d[7]=b.w;
}

DEV void store8(float* p, const float* d) {
  *(float4*)p       = make_float4(d[0], d[1], d[2], d[3]);
  *(float4*)(p + 4) = make_float4(d[4], d[5], d[6], d[7]);
}

DEV void project8(float* x) {
  float n2 = dot8(x, x) + 1e-15f;
  if (n2 > MAXN2) {
    float s = MAXN * rsqf(n2);
    #pragma unroll
    for (int i = 0; i < 8; ++i) x[i] *= s;
  }
}

DEV void logmap0_8(float* o, const float* x) {
  float t[8];
  #pragma unroll
  for (int i = 0; i < 8; ++i) t[i] = x[i];
  project8(t);
  float n2 = dot8(t, t) + 1e-15f;
  float rs = rsqf(n2);
  float n  = n2 * rs;
  float c  = fminf(n, 1.0f - 1e-7f);
  float at = 0.34657359f * (__log2f(1.0f + c) - __log2f(1.0f - c));
  float r  = at * rs;
  #pragma unroll
  for (int i = 0; i < 8; ++i) o[i] = t[i] * r;
}

DEV void expmap0_8(float* o, const float* u) {
  float n2 = dot8(u, u) + 1e-15f;
  float rs = rsqf(n2);
  float n  = n2 * rs;
  float e  = __expf(2.0f * n);
  float th = 1.0f - 2.0f * rcpf(e + 1.0f);
  float r  = th * rs;
  #pragma unroll
  for (int i = 0; i < 8; ++i) o[i] = u[i] * r;
  project8(o);
}

DEV void matvec8(float* o, const float* M, const float* u) {
  #pragma unroll
  for (int e = 0; e < 8; ++e) o[e] = dot8(M + 8*e, u);
}

// ---------------- DPP helpers ----------------
template<int CTRL>
DEV float dppf(float x) {
  int xi = __float_as_int(x);
  return __int_as_float(__builtin_amdgcn_update_dpp(xi, xi, CTRL, 0xF, 0xF, true));
}
// xor1=quad_perm 0xB1; xor2=0x4E; xor3=0x1B; xor7=row_half_mirror 0x141;
// half-swap (lane^8 within 16) = row_ror:8 = 0x128.

DEV float grp8sum(float x) {
  x += dppf<0xB1>(x);
  x += dppf<0x4E>(x);
  x += dppf<0x141>(x);
  return x;
}

DEV void red2(float& a, float& b) {
  float t0 = dppf<0xB1>(a),  t1 = dppf<0xB1>(b);  a += t0; b += t1;
  float t2 = dppf<0x4E>(a),  t3 = dppf<0x4E>(b);  a += t2; b += t3;
  float t4 = dppf<0x141>(a), t5 = dppf<0x141>(b); a += t4; b += t5;
}

DEV void red3(float& a, float& b, float& c) {
  float t0 = dppf<0xB1>(a),  t1 = dppf<0xB1>(b),  t2 = dppf<0xB1>(c);
  a += t0; b += t1; c += t2;
  float t3 = dppf<0x4E>(a),  t4 = dppf<0x4E>(b),  t5 = dppf<0x4E>(c);
  a += t3; b += t4; c += t5;
  float t6 = dppf<0x141>(a), t7 = dppf<0x141>(b), t8 = dppf<0x141>(c);
  a += t6; b += t7; c += t8;
}

DEV void red4(float& a, float& b, float& c, float& d) {
  float t0 = dppf<0xB1>(a),  t1 = dppf<0xB1>(b),  t2 = dppf<0xB1>(c),  t3 = dppf<0xB1>(d);
  a += t0; b += t1; c += t2; d += t3;
  float t4 = dppf<0x4E>(a),  t5 = dppf<0x4E>(b),  t6 = dppf<0x4E>(c),  t7 = dppf<0x4E>(d);
  a += t4; b += t5; c += t6; d += t7;
  float t8 = dppf<0x141>(a), t9 = dppf<0x141>(b), ta = dppf<0x141>(c), tb = dppf<0x141>(d);
  a += t8; b += t9; c += ta; d += tb;
}

#define MV8(w, u0,u1,u2,u3,u4,u5,u6,u7) \
  ((((w[0]*(u0)) + (w[1]*(u1))) + ((w[2]*(u2)) + (w[3]*(u3)))) + \
   (((w[4]*(u4)) + (w[5]*(u5))) + ((w[6]*(u6)) + (w[7]*(u7)))))

// logmap scale: artanh(min(|x|,1-1e-7)) / |x|, from squared norm
DEV float lgscale(float n2) {
  float n2p = n2 + 1e-15f;
  float rs  = rsqf(n2p);
  float n   = n2p * rs;
  float c   = fminf(n, 1.0f - 1e-7f);
  float at  = 0.34657359f * (__log2f(1.0f + c) - __log2f(1.0f - c));
  return at * rs;
}

DEV float sigm(float x) { return rcpf(1.0f + __expf(-x)); }

// Flattened gate: g2 = project((expmap0(v) (+) c) (+) b) = P*v + Q*c + R*b.
// Inputs: n2v=|v|^2, dvc=<v,c>, dvb=<v,b>, c2=|c|^2, b2=|b|^2, cb=<c,b>.
DEV void gate_coeffs(float n2v, float dvc, float dvb,
                     float c2, float b2, float cb,
                     float& P, float& Q, float& R, float& g2_2) {
  float n2p = n2v + 1e-15f;
  float rsv = rsqf(n2p);
  float nv  = n2p * rsv;
  float e   = __expf(2.0f * nv);
  float th  = 1.0f - 2.0f * rcpf(e + 1.0f);
  float a_scale = th * rsv;            // a = a_scale * v
  float a2  = th * th;
  if (a2 > MAXN2) { float s = MAXN * rsqf(a2); a_scale *= s; a2 = MAXN2; }
  // madd1: a (+) c
  float xy1 = a_scale * dvc;
  float cx1 = 1.0f + 2.0f*xy1 + c2;
  float cy1 = 1.0f - a2;
  float rd1 = rcpf(1.0f + 2.0f*xy1 + a2*c2);
  float num2 = (cx1*cx1)*a2 + 2.0f*(cx1*cy1)*xy1 + (cy1*cy1)*c2;
  float g1_2 = num2 * (rd1*rd1);
  float e1 = rd1;
  if (g1_2 > MAXN2) { e1 *= MAXN * rsqf(g1_2); g1_2 = MAXN2; }
  // madd2: g1 (+) b, with <g1,b> from scalars
  float ab  = a_scale * dvb;
  float xy2 = e1 * (cx1*ab + cy1*cb);
  float cx2 = 1.0f + 2.0f*xy2 + b2;
  float cy2 = 1.0f - g1_2;
  float rd2 = rcpf(1.0f + 2.0f*xy2 + g1_2*b2);
  float n2b = (cx2*cx2)*g1_2 + 2.0f*(cx2*cy2)*xy2 + (cy2*cy2)*b2;
  g2_2 = n2b * (rd2*rd2);
  float e2s = rd2;
  if (g2_2 > MAXN2) { e2s *= MAXN * rsqf(g2_2); g2_2 = MAXN2; }
  float t = e2s * cx2 * e1;
  P = t * cx1 * a_scale;
  Q = t * cy1;
  R = e2s * cy2;
}

// ---------------- input pre-pass ----------------
__global__ void prep_kernel(const int* __restrict__ x, const float* __restrict__ wemb,
                            const float* __restrict__ Uz, const float* __restrict__ Ur,
                            const float* __restrict__ Uh,
                            const float* __restrict__ bzp, const float* __restrict__ brp,
                            const float* __restrict__ bhp,
                            float* __restrict__ axz, float* __restrict__ axr, float* __restrict__ axh,
                            float* __restrict__ scB)
{
  int t = blockIdx.x * 256 + threadIdx.x;
  if (t >= BB * SS * HH) return;
  int hh = t & (HH - 1);
  int bs = t >> 5;
  int idx = x[bs];
  float we[8]; load8(we, wemb + ((size_t)idx * HH + hh) * 8);
  project8(we);
  float lx[8]; logmap0_8(lx, we);
  float bz[8], br[8], bh[8];
  load8(bz, bzp); load8(br, brp); load8(bh, bhp);
  float v[8], az[8], ar[8], ah[8];
  matvec8(v, Uz, lx); expmap0_8(az, v); store8(axz + (size_t)t * 8, az);
  matvec8(v, Ur, lx); expmap0_8(ar, v); store8(axr + (size_t)t * 8, ar);
  matvec8(v, Uh, lx); expmap0_8(ah, v); store8(axh + (size_t)t * 8, ah);
  float cz2 = dot8(az, az), cr2 = dot8(ar, ar), ch2 = dot8(ah, ah);
  float czb = dot8(az, bz), crb = dot8(ar, br), chb = dot8(ah, bh);
  *(float4*)(scB + (size_t)t * 8)     = make_float4(cz2, cr2, ch2, czb);
  *(float4*)(scB + (size_t)t * 8 + 4) = make_float4(crb, chb, 0.0f, 0.0f);
}

// ---------------- label pre-pass ----------------
__global__ void label_kernel(const float* __restrict__ lemb,
                             float* __restrict__ labP, float* __restrict__ l2o)
{
  int t = blockIdx.x * 256 + threadIdx.x;
  if (t >= LL * HH) return;
  float lv[8]; load8(lv, lemb + (size_t)t * 8);
  project8(lv);
  store8(labP + (size_t)t * 8, lv);
  l2o[t] = dot8(lv, lv);
}

// ---------------- GRU scan: 16 lanes per chain (z/r merged in halves) ----------------
__global__ __launch_bounds__(64, 1) void gru_kernel(
    const float* __restrict__ Wzp, const float* __restrict__ Wrp, const float* __restrict__ Whp,
    const float* __restrict__ bzp, const float* __restrict__ brp, const float* __restrict__ bhp,
    const float* __restrict__ axz, const float* __restrict__ axr, const float* __restrict__ axh,
    const float* __restrict__ scB,
    float* __restrict__ enc, float* __restrict__ e2out)
{
  const int lane = threadIdx.x;          // 0..63
  const int d    = lane & 7;             // dim
  const bool hif = (lane & 8) != 0;      // half: 0 -> z gate, 1 -> r gate
  const int cg   = lane >> 4;            // chain within block (0..3)
  const int chain = blockIdx.x * 4 + cg;
  const int b = chain >> 5;
  const int h = chain & 31;

  const float* Wg     = hif ? Wrp : Wzp;
  const float* cgbase = hif ? axr : axz;

  float wg[8], wh[8];
  #pragma unroll
  for (int k = 0; k < 8; ++k) {
    wg[k] = Wg[d*8 + (d^k)];
    wh[k] = Whp[d*8 + (d^k)];
  }
  float bgv = (hif ? brp : bzp)[d];
  float bhv = bhp[d];
  float bg2 = grp8sum(bgv*bgv);          // |bz|^2 (half0) or |br|^2 (half1)
  float bh2 = grp8sum(bhv*bhv);

  float hv = 0.0f, h2 = 0.0f;

  size_t voff = ((size_t)b * SS * HH + h) * 8 + d;
  size_t soff = (size_t)b * SS * HH + h;

  float cgv = cgbase[voff];
  float chv = axh[voff];
  float4 sA = *(const float4*)(scB + soff * 8);
  float4 sB = *(const float4*)(scB + soff * 8 + 4);

  #pragma unroll 1
  for (int s = 0; s < SS; ++s) {
    size_t nvoff = voff + HH*8, nsoff = soff + HH;
    size_t pv = (s + 1 < SS) ? nvoff : voff;
    size_t ps = (s + 1 < SS) ? nsoff : soff;
    float ncg = cgbase[pv];
    float nch = axh[pv];
    float4 nsA = *(const float4*)(scB + ps * 8);
    float4 nsB = *(const float4*)(scB + ps * 8 + 4);

    // unpack per-half scalars: layout {cz2,cr2,ch2,czb, crb,chb,-,-}
    float c2g  = hif ? sA.y : sA.x;
    float cbg  = hif ? sB.x : sA.w;
    float ch2v = sA.z;
    float chbv = sB.y;

    // step-start reductions (shadowed by logmap h)
    float dhch = hv * chv, dhbh = hv * bhv;
    red2(dhch, dhbh);

    // lh = logmap0(h)
    float lsc = lgscale(h2);
    float lh  = hv * lsc;

    // shared permutes + gate matvec (z in half0, r in half1)
    float l1 = dppf<0xB1>(lh), l2 = dppf<0x4E>(lh), l3 = dppf<0x1B>(lh), l7 = dppf<0x141>(lh);
    float l4 = dppf<0x1B>(l7), l5 = dppf<0x4E>(l7), l6 = dppf<0xB1>(l7);
    float vg = MV8(wg, lh, l1, l2, l3, l4, l5, l6, l7);

    float n2g = vg*vg, dgc = vg*cgv, dgb = vg*bgv;
    red3(n2g, dgc, dgb);

    float P, Q, R, g22;
    gate_coeffs(n2g, dgc, dgb, c2g, bg2, cbg, P, Q, R, g22);
    float g2  = P*vg + Q*cgv + R*bgv;
    float gsv = sigm(lgscale(g22) * g2);   // zv (half0) / rv (half1)
    float gsw = dppf<0x128>(gsv);          // swap halves
    float rv  = hif ? gsv : gsw;
    float zv  = hif ? gsw : gsv;

    // h_tilde: logmap0(expmap0(r*lh)) == r*lh (norm < artanh(MAX_NORM))
    float u = rv * lh;
    float u1 = dppf<0xB1>(u), u2p = dppf<0x4E>(u), u3 = dppf<0x1B>(u), u7 = dppf<0x141>(u);
    float u4 = dppf<0x1B>(u7), u5 = dppf<0x4E>(u7), u6 = dppf<0xB1>(u7);
    float vh = MV8(wh, u, u1, u2p, u3, u4, u5, u6, u7);

    float n2h = vh*vh, rhc = vh*chv, rhb = vh*bhv, dhv = hv*vh;
    red4(n2h, rhc, rhb, dhv);

    float Ph, Qh, Rh, t42;
    gate_coeffs(n2h, rhc, rhb, ch2v, bh2, chbv, Ph, Qh, Rh, t42);
    float t4   = Ph*vh + Qh*chv + Rh*bhv;
    float dht4 = Ph*dhv + Qh*dhch + Rh*dhbh;   // <h, t4>

    // m = (-h) (+) t4
    float xym = -dht4;
    float cxm = 1.0f + 2.0f*xym + t42;
    float cym = 1.0f - h2;
    float rdm = rcpf(1.0f + 2.0f*xym + h2*t42);
    float m2  = ((cxm*cxm)*h2 + 2.0f*(cxm*cym)*xym + (cym*cym)*t42) * (rdm*rdm);
    float em  = rdm;
    if (m2 > MAXN2) { em *= MAXN * rsqf(m2); m2 = MAXN2; }
    float md = em * (cym*t4 - cxm*hv);

    // w = z * logmap0(m)
    float lmm = lgscale(m2);
    float w   = zv * (lmm * md);

    float n2w = w*w, dhw = hv*w;
    red2(n2w, dhw);

    // ee = expmap0(w)
    float n2wp = n2w + 1e-15f;
    float rsw = rsqf(n2wp);
    float nw  = n2wp * rsw;
    float ew  = __expf(2.0f * nw);
    float thw = 1.0f - 2.0f * rcpf(ew + 1.0f);
    float esc = thw * rsw;                  // ee = esc * w
    float ee2 = thw * thw;
    if (ee2 > MAXN2) { esc *= MAXN * rsqf(ee2); ee2 = MAXN2; }

    // hn = h (+) ee
    float xyf = esc * dhw;
    float cxf = 1.0f + 2.0f*xyf + ee2;
    float cyf = 1.0f - h2;
    float rdf = rcpf(1.0f + 2.0f*xyf + h2*ee2);
    float hn2 = ((cxf*cxf)*h2 + 2.0f*(cxf*cyf)*xyf + (cyf*cyf)*ee2) * (rdf*rdf);
    float ef  = rdf;
    if (hn2 > MAXN2) { ef *= MAXN * rsqf(hn2); hn2 = MAXN2; }
    float hn = (ef*cxf)*hv + (ef*cyf*esc)*w;

    if (!hif) enc[voff] = hn;
    if ((lane & 15) == 0) e2out[soff] = hn2;

    hv = hn; h2 = hn2;
    cgv = ncg; chv = nch; sA = nsA; sB = nsB;
    voff = nvoff; soff = nsoff;
  }
}

// ---------------- poincare distance sums -> inter [B,L,S], 2x2 per thread ----------------
DEV float pdist(float ee, float ll, float el) {
  float d2  = ee + ll - 2.0f * el;
  float den = fmaxf((1.0f - ee) * (1.0f - ll), 1e-15f);
  float z   = 1.0f + 2.0f * d2 * rcpf(den);
  z = fmaxf(z, 1.0f + 1e-7f);
  return 0.69314718f * __log2f(z + sqrtf(z*z - 1.0f));
}

__global__ __launch_bounds__(256) void dist_kernel(
    const float* __restrict__ enc, const float* __restrict__ e2,
    const float* __restrict__ labP, const float* __restrict__ l2,
    float* __restrict__ inter)
{
  int blk = blockIdx.x;
  int lt = blk & 15, st = (blk >> 4) & 15, b = blk >> 8;
  int li = threadIdx.x & 15, si = threadIdx.x >> 4;
  int s = st * 32 + si * 2, l = lt * 32 + li * 2;

  const float* er0 = enc + ((size_t)b * SS + s) * HH * 8;
  const float* er1 = er0 + HH * 8;
  const float* e20 = e2 + ((size_t)b * SS + s) * HH;
  const float* e21 = e20 + HH;
  const float* lr0 = labP + (size_t)l * HH * 8;
  const float* lr1 = lr0 + HH * 8;
  const float* l20 = l2 + (size_t)l * HH;
  const float* l21 = l20 + HH;

  float a00 = 0.f, a01 = 0.f, a10 = 0.f, a11 = 0.f;
  #pragma unroll 2
  for (int hh = 0; hh < HH; ++hh) {
    float ev0[8], ev1[8], lv0[8], lv1[8];
    load8(ev0, er0 + hh * 8); load8(ev1, er1 + hh * 8);
    load8(lv0, lr0 + hh * 8); load8(lv1, lr1 + hh * 8);
    float x00 = dot8(ev0, lv0), x01 = dot8(ev0, lv1);
    float x10 = dot8(ev1, lv0), x11 = dot8(ev1, lv1);
    float e0v = e20[hh], e1v = e21[hh], l0v = l20[hh], l1v = l21[hh];
    a00 += pdist(e0v, l0v, x00);
    a01 += pdist(e0v, l1v, x01);
    a10 += pdist(e1v, l0v, x10);
    a11 += pdist(e1v, l1v, x11);
  }
  float* o0 = inter + ((size_t)b * LL + l) * SS + s;
  o0[0] = a00; o0[1] = a10;
  o0[SS] = a01; o0[SS + 1] = a11;
}

// ---------------- MLP stage 1: h = relu(inter @ W1^T + b1) ----------------
__global__ __launch_bounds__(256) void mlp1_kernel(
    const float* __restrict__ inter, const float* __restrict__ W1,
    const float* __restrict__ b1, float* __restrict__ hbuf)
{
  __shared__ float As[32][33];
  __shared__ float Bs[32][33];
  int t = threadIdx.x;
  int nt = blockIdx.x & 7, mt = blockIdx.x >> 3;
  int row0 = mt * 32, j0 = nt * 32;
  int li = t >> 4, ji = t & 15;
  float acc00 = 0.f, acc01 = 0.f, acc10 = 0.f, acc11 = 0.f;

  for (int k0 = 0; k0 < 512; k0 += 32) {
    __syncthreads();
    {
      int l = t >> 3, kk = (t & 7) * 4;
      float4 v = *(const float4*)(inter + (size_t)(row0 + l) * 512 + k0 + kk);
      As[l][kk] = v.x; As[l][kk+1] = v.y; As[l][kk+2] = v.z; As[l][kk+3] = v.w;
      float4 w = *(const float4*)(W1 + (size_t)(j0 + l) * 512 + k0 + kk);
      Bs[kk][l] = w.x; Bs[kk+1][l] = w.y; Bs[kk+2][l] = w.z; Bs[kk+3][l] = w.w;
    }
    __syncthreads();
    #pragma unroll
    for (int kk = 0; kk < 32; ++kk) {
      float a0 = As[li][kk],  a1 = As[li + 16][kk];
      float b0 = Bs[kk][ji],  b1v = Bs[kk][ji + 16];
      acc00 = fmaf(a0, b0, acc00);
      acc01 = fmaf(a0, b1v, acc01);
      acc10 = fmaf(a1, b0, acc10);
      acc11 = fmaf(a1, b1v, acc11);
    }
  }
  float bj0 = b1[j0 + ji], bj1 = b1[j0 + ji + 16];
  hbuf[(size_t)(row0 + li)      * 256 + j0 + ji]      = fmaxf(acc00 + bj0, 0.f);
  hbuf[(size_t)(row0 + li)      * 256 + j0 + ji + 16] = fmaxf(acc01 + bj1, 0.f);
  hbuf[(size_t)(row0 + li + 16) * 256 + j0 + ji]      = fmaxf(acc10 + bj0, 0.f);
  hbuf[(size_t)(row0 + li + 16) * 256 + j0 + ji + 16] = fmaxf(acc11 + bj1, 0.f);
}

// ---------------- MLP stage 2: out = h @ W2^T + b2 ----------------
__global__ void mlp2_kernel(const float* __restrict__ hbuf, const float* __restrict__ W2,
                            const float* __restrict__ b2, float* __restrict__ out)
{
  int t = threadIdx.x;
  int row = blockIdx.x * 4 + (t >> 6);
  int lane = t & 63;
  float v = 0.f;
  #pragma unroll
  for (int p = 0; p < 4; ++p) {
    int j = lane + p * 64;
    v = fmaf(hbuf[(size_t)row * 256 + j], W2[j], v);
  }
  #pragma unroll
  for (int off = 32; off > 0; off >>= 1) v += __shfl_xor(v, off);
  if (lane == 0) out[row] = v + b2[0];
}

extern "C" void kernel_launch(void* const* d_in, const int* in_sizes, int n_in,
                              void* d_out, int out_size, void* d_ws, size_t ws_size,
                              hipStream_t stream) {
  (void)in_sizes; (void)n_in; (void)out_size; (void)ws_size;
  const int*   x    = (const int*)d_in[0];
  const float* wemb = (const float*)d_in[1];
  const float* lemb = (const float*)d_in[2];
  const float* Wz = (const float*)d_in[3];
  const float* Wr = (const float*)d_in[4];
  const float* Wh = (const float*)d_in[5];
  const float* Uz = (const float*)d_in[6];
  const float* Ur = (const float*)d_in[7];
  const float* Uh = (const float*)d_in[8];
  const float* bz = (const float*)d_in[9];
  const float* br = (const float*)d_in[10];
  const float* bh = (const float*)d_in[11];
  const float* W1 = (const float*)d_in[12];
  const float* b1 = (const float*)d_in[13];
  const float* W2 = (const float*)d_in[14];
  const float* b2 = (const float*)d_in[15];
  float* out = (float*)d_out;

  float* p = (float*)d_ws;
  const size_t NBSH  = (size_t)BB * SS * HH;       // 65536
  const size_t NBSH8 = NBSH * 8;                   // 524288
  float* axz  = p; p += NBSH8;
  float* axr  = p; p += NBSH8;
  float* axh  = p; p += NBSH8;
  float* scB  = p; p += NBSH8;                     // packed per-(b,s,h) scalars
  float* enc  = p; p += NBSH8;
  float* e2   = p; p += NBSH;
  float* labP = p; p += (size_t)LL * HH * 8;       // 131072
  float* l2   = p; p += (size_t)LL * HH;           // 16384
  float* inter= p; p += (size_t)BB * LL * SS;      // 1048576
  float* hbuf = p; p += (size_t)BB * LL * 256;     // 524288

  prep_kernel <<<(BB * SS * HH) / 256, 256, 0, stream>>>(x, wemb, Uz, Ur, Uh, bz, br, bh,
                                                         axz, axr, axh, scB);
  label_kernel<<<(LL * HH) / 256, 256, 0, stream>>>(lemb, labP, l2);
  gru_kernel  <<<32, 64, 0, stream>>>(Wz, Wr, Wh, bz, br, bh,
                                      axz, axr, axh, scB, enc, e2);
  dist_kernel <<<BB * (SS / 32) * (LL / 32), 256, 0, stream>>>(enc, e2, labP, l2, inter);
  mlp1_kernel <<<512, 256, 0, stream>>>(inter, W1, b1, hbuf);
  mlp2_kernel <<<512, 256, 0, stream>>>(hbuf, W2, b2, out);
}